// Round 8
// baseline (677.000 us; speedup 1.0000x reference)
//
#include <hip/hip_runtime.h>
#include <cmath>

// Problem constants (fixed by the reference).
#define Bn    16384
#define Tn    2048
#define HIDn  5
#define NBINS 2048

typedef float v2f __attribute__((ext_vector_type(2)));

static __device__ __forceinline__ float rcp_fast(float v) {
    return __builtin_amdgcn_rcpf(v);
}
static __device__ __forceinline__ float exp2_fast(float v) {
    return __builtin_amdgcn_exp2f(v);
}
static __device__ __forceinline__ float med3(float x, float lo, float hi) {
    return __builtin_amdgcn_fmed3f(x, lo, hi);   // 1-op clamp
}

// Broadcast lane (8g + K) to all lanes of each 8-lane group (ds_swizzle BitMode:
// new_src = (lane & 0x18) | K).
template <int K>
static __device__ __forceinline__ float bcast8(float v) {
    return __int_as_float(
        __builtin_amdgcn_ds_swizzle(__float_as_int(v), (K << 5) | 0x18));
}

// Host-computed base-G Chebyshev coefficients (NAMED FIELDS ONLY — R6 showed
// pointer/array indexing of a by-value kernarg struct goes to scratch and puts
// ~300cy of loads on the recurrence chain; R7 verified named fields hoist).
//   G(y) = tanh(4*sqrt(y))/(4*sqrt(y)) on y in [0,1].
//   sigma(p) = 0.5 + (2w)*G14(w^2),  w = clamp(p/8, +-1)   [2x via wA+wA]
//   tanh(g)/4 = wg*G10(wg^2),        wg = clamp(g/4, +-1)
//   tanh(c)   = (4*cc)*G14(cc^2),    cc = clamp(c/4, +-1)  [4x via 4*oo]
struct GCoef {
    float q0, q1, q2, q3, q4, q5, q6, q7, q8, q9, q10, q11, q12, q13; // G, N=14
    float g0, g1, g2, g3, g4, g5, g6, g7, g8, g9;                     // G, N=10
};

// ---------------------------------------------------------------------------
// Pass 0: zero the global histogram bins (ws is poisoned 0xAA by the harness).
// ---------------------------------------------------------------------------
__global__ void zero_kernel(int* __restrict__ gbins) {
    gbins[blockIdx.x * 256 + threadIdx.x] = 0;
}

// ---------------------------------------------------------------------------
// Pass 1: lengths[b] = count of nonzero x[b,t] (exact reference mask.sum
// semantics) + histogram of descending-key d = NBINS - len.
// ---------------------------------------------------------------------------
__global__ __launch_bounds__(256) void len_kernel(const float* __restrict__ x,
                                                  int* __restrict__ lengths,
                                                  int* __restrict__ gbins) {
    const int gtid = blockIdx.x * 256 + threadIdx.x;
    const int row  = gtid >> 6;
    const int lane = threadIdx.x & 63;
    const float4* r = reinterpret_cast<const float4*>(x + (size_t)row * Tn);
    int cnt = 0;
    #pragma unroll
    for (int i = 0; i < Tn / 4 / 64; ++i) {
        float4 v = r[i * 64 + lane];
        cnt += (v.x != 0.0f) + (v.y != 0.0f) + (v.z != 0.0f) + (v.w != 0.0f);
    }
    #pragma unroll
    for (int off = 32; off > 0; off >>= 1) cnt += __shfl_xor(cnt, off, 64);
    if (lane == 0) {
        lengths[row] = cnt;
        const int d = max(0, min(NBINS - 1, NBINS - cnt));
        atomicAdd(&gbins[d], 1);
    }
}

// ---------------------------------------------------------------------------
// Pass 1.5: scan the histogram + scatter -> perm[] sorted by length DESC.
// ---------------------------------------------------------------------------
__global__ __launch_bounds__(1024) void sort_kernel(const int* __restrict__ lengths,
                                                    const int* __restrict__ gbins,
                                                    int* __restrict__ perm) {
    __shared__ int bins[NBINS];
    __shared__ int bsum[1024];
    const int tid = threadIdx.x;
    bins[tid]        = gbins[tid];
    bins[tid + 1024] = gbins[tid + 1024];
    __syncthreads();
    const int a0 = bins[2 * tid], a1 = bins[2 * tid + 1];
    const int s = a0 + a1;
    bsum[tid] = s;
    __syncthreads();
    int acc = s;
    for (int off = 1; off < 1024; off <<= 1) {
        int v = (tid >= off) ? bsum[tid - off] : 0;
        __syncthreads();
        acc += v;
        bsum[tid] = acc;
        __syncthreads();
    }
    const int excl = acc - s;
    bins[2 * tid]     = excl;
    bins[2 * tid + 1] = excl + a0;
    __syncthreads();
    for (int i = tid; i < Bn; i += 1024) {
        int d = NBINS - lengths[i];
        d = max(0, min(NBINS - 1, d));
        const int p = atomicAdd(&bins[d], 1);
        perm[p] = i;
    }
}

// ---------------------------------------------------------------------------
// Pass 2: LSTM. R5 structure (8 lanes/group, lane k=min(lsub,4) owns hidden k,
// ds_swizzle broadcast, 2 waves/SIMD, cndmask commit, POST-LOOP store — R7
// proved the in-loop predicated store costs ~100cy/step in schedule damage).
// This round: ALL-POLY activations (R6's verified math, R7's verified codegen):
//   - sigma(i),sigma(f): packed Estrin-14 of base G  (~56cy chain)
//   - tanh(g): scalar Estrin-10                       (parallel path)
//   - spine tanh(c): scalar Estrin-14                 (~56cy chain)
//   - sigma(o): exp2+rcp, fully off-chain; its 4x spine-scale fold rides here
// Chain ~ ladder 48 + sigma 56 + cn 16 + spine 56 + hn 8 + commit 8 +
// bcast 130 = 330 (R5: 466). Trans/step 5 -> 1 (kills the TRANS-pipe co-wave
// contention that tracked the residue: R0~204 vs R5~266 vs R7~296).
// No setprio: symmetric lockstep waves are the GEMM case (m190: it hurts).
// ---------------------------------------------------------------------------
__global__ __launch_bounds__(256, 2) void lstm_kernel(const float* __restrict__ x,
                                                      const float* __restrict__ Wih,
                                                      const float* __restrict__ Whh,
                                                      const float* __restrict__ bih,
                                                      const float* __restrict__ bhh,
                                                      const int* __restrict__ lengths,
                                                      const int* __restrict__ perm,
                                                      float* __restrict__ out,
                                                      GCoef GC) {
    const int gtid = blockIdx.x * 256 + threadIdx.x;
    const int grp  = gtid >> 3;              // group-of-8 index = sorted rank
    const int lsub = threadIdx.x & 7;
    const int k    = min(lsub, 4);           // owned hidden index

    const int b   = perm[grp];
    const int len = lengths[b];

    // Gate rows: i=k, f=5+k, g=10+k, o=15+k. Pair A=(i,f) scaled 1/8 (poly
    // sigma arg), pair B=(g,o): g scaled 1/4 (poly tanh arg), o scaled
    // -log2e (exp2 sigmoid, off-chain).
    const float SA = 0.125f;
    const float SG = 0.25f;
    const float SO = -1.4426950408889634f;
    v2f wihA, wihB, bA, bB, whhA[HIDn], whhB[HIDn];
    {
        const int gi = k, gf = 5 + k, gg = 10 + k, go = 15 + k;
        wihA = (v2f){ Wih[gi] * SA, Wih[gf] * SA };
        wihB = (v2f){ Wih[gg] * SG, Wih[go] * SO };
        bA   = (v2f){ (bih[gi] + bhh[gi]) * SA, (bih[gf] + bhh[gf]) * SA };
        bB   = (v2f){ (bih[gg] + bhh[gg]) * SG, (bih[go] + bhh[go]) * SO };
        #pragma unroll
        for (int kk = 0; kk < HIDn; ++kk) {
            whhA[kk] = (v2f){ Whh[gi * HIDn + kk] * SA, Whh[gf * HIDn + kk] * SA };
            whhB[kk] = (v2f){ Whh[gg * HIDn + kk] * SG, Whh[go * HIDn + kk] * SO };
        }
    }

    const float* xrow = x + (size_t)b * Tn;
    float h0 = 0, h1 = 0, h2 = 0, h3 = 0, h4 = 0;
    float hq = 0, c4 = 0;                    // c kept in c/4 domain

    float4 xq = *reinterpret_cast<const float4*>(xrow);
    for (int t = 0; __any(t < len); t += 4) {
        const float4 xn = *reinterpret_cast<const float4*>(xrow + min(t + 4, Tn - 4));
        const float xs[4] = { xq.x, xq.y, xq.z, xq.w };
        #pragma unroll
        for (int s = 0; s < 4; ++s) {
            const float xv = xs[s];
            // Packed pre-activations (serial ladder, R5-verbatim).
            v2f pA = xv * wihA + bA;
            v2f pB = xv * wihB + bB;
            pA = h0 * whhA[0] + pA;  pB = h0 * whhB[0] + pB;
            pA = h1 * whhA[1] + pA;  pB = h1 * whhB[1] + pB;
            pA = h2 * whhA[2] + pA;  pB = h2 * whhB[2] + pB;
            pA = h3 * whhA[3] + pA;  pB = h3 * whhB[3] + pB;
            pA = h4 * whhA[4] + pA;  pB = h4 * whhB[4] + pB;

            // sigma(i), sigma(f): packed Estrin-14 of base G.
            v2f wA;
            wA.x = med3(pA.x, -1.0f, 1.0f);
            wA.y = med3(pA.y, -1.0f, 1.0f);
            const v2f zA  = wA * wA;
            const v2f wA2 = wA + wA;               // 2x fold, off-chain
            const v2f a0 = zA * GC.q1  + GC.q0;
            const v2f a1 = zA * GC.q3  + GC.q2;
            const v2f a2 = zA * GC.q5  + GC.q4;
            const v2f a3 = zA * GC.q7  + GC.q6;
            const v2f a4 = zA * GC.q9  + GC.q8;
            const v2f a5 = zA * GC.q11 + GC.q10;
            const v2f a6 = zA * GC.q13 + GC.q12;
            const v2f z2 = zA * zA, z4 = z2 * z2, z8 = z4 * z4;
            const v2f b0 = z2 * a1 + a0, b1 = z2 * a3 + a2, b2 = z2 * a5 + a4;
            const v2f d0 = z4 * b1 + b0, d1 = z4 * a6 + b2;
            const v2f Ps = z8 * d1 + d0;
            const v2f sAB = wA2 * Ps + 0.5f;       // (sigma_i, sigma_f)

            // tanh(g)/4: scalar Estrin-10 of base G.
            const float wg = med3(pB.x, -1.0f, 1.0f);
            const float ug = wg * wg;
            const float e0 = fmaf(ug, GC.g1, GC.g0);
            const float e1 = fmaf(ug, GC.g3, GC.g2);
            const float e2 = fmaf(ug, GC.g5, GC.g4);
            const float e3 = fmaf(ug, GC.g7, GC.g6);
            const float e4 = fmaf(ug, GC.g9, GC.g8);
            const float ug2 = ug * ug, ug4 = ug2 * ug2, ug8 = ug4 * ug4;
            const float f0 = fmaf(ug2, e1, e0), f1 = fmaf(ug2, e3, e2);
            const float Pg = fmaf(ug8, e4, fmaf(ug4, f1, f0));
            const float tg4 = wg * Pg;             // tanh(g)/4

            // sigma(o): exp2 path, off-chain; carries the spine's 4x fold.
            const float eO  = exp2_fast(pB.y);
            const float oo  = rcp_fast(1.0f + eO);
            const float oo4 = 4.0f * oo;

            // c/4 update.
            const float cn4 = fmaf(sAB.y, c4, sAB.x * tg4);

            // Spine tanh(c) via scalar Estrin-14 of base G.
            const float cc = med3(cn4, -1.0f, 1.0f);
            const float uc = cc * cc;
            const float m0 = fmaf(uc, GC.q1,  GC.q0);
            const float m1 = fmaf(uc, GC.q3,  GC.q2);
            const float m2 = fmaf(uc, GC.q5,  GC.q4);
            const float m3 = fmaf(uc, GC.q7,  GC.q6);
            const float m4 = fmaf(uc, GC.q9,  GC.q8);
            const float m5 = fmaf(uc, GC.q11, GC.q10);
            const float m6 = fmaf(uc, GC.q13, GC.q12);
            const float uc2 = uc * uc, uc4 = uc2 * uc2, uc8 = uc4 * uc4;
            const float n0 = fmaf(uc2, m1, m0);
            const float n1 = fmaf(uc2, m3, m2);
            const float n2 = fmaf(uc2, m5, m4);
            const float o0 = fmaf(uc4, n1, n0);
            const float o1 = fmaf(uc4, m6, n2);
            const float Pc = fmaf(uc8, o1, o0);
            const float hn = (cc * Pc) * oo4;      // tanh(c) * sigma(o)

            // Conditional commit (cndmask); frozen past len. Store post-loop.
            const bool upd = (t + s) < len;
            c4 = upd ? cn4 : c4;
            hq = upd ? hn : hq;

            h0 = bcast8<0>(hq);
            h1 = bcast8<1>(hq);
            h2 = bcast8<2>(hq);
            h3 = bcast8<3>(hq);
            h4 = bcast8<4>(hq);
        }
        xq = xn;
    }

    if (lsub < HIDn) out[(size_t)b * HIDn + lsub] = hq;
}

// ---------------------------------------------------------------------------
// Host: Chebyshev interpolation of G(y) = tanh(4*sqrt(y))/(4*sqrt(y)) on
// y in [0,1] (Newton divided differences at Chebyshev nodes, double precision,
// expanded to monomials). Verified on-device in round 6 (passed, 3.9e-3).
// ---------------------------------------------------------------------------
static void tanh_base_poly(int N, double* c) {
    double yj[16], fj[16];
    for (int j = 0; j < N; ++j) {
        const double v = cos(M_PI * (2 * j + 1) / (2.0 * N));
        const double y = 0.5 + 0.5 * v;
        const double xx = 4.0 * sqrt(y);
        yj[j] = y;
        fj[j] = tanh(xx) / xx;
    }
    for (int k = 1; k < N; ++k)
        for (int j = N - 1; j >= k; --j)
            fj[j] = (fj[j] - fj[j - 1]) / (yj[j] - yj[j - k]);
    for (int i = 0; i < 16; ++i) c[i] = 0.0;
    c[0] = fj[N - 1];
    int deg = 0;
    for (int j = N - 2; j >= 0; --j) {
        for (int i = deg; i >= 0; --i) {
            c[i + 1] += c[i];
            c[i] = -yj[j] * c[i];
        }
        ++deg;
        c[0] += fj[j];
    }
}

extern "C" void kernel_launch(void* const* d_in, const int* in_sizes, int n_in,
                              void* d_out, int out_size, void* d_ws, size_t ws_size,
                              hipStream_t stream) {
    const float* x   = (const float*)d_in[0];  // [B,1,T,1]
    const float* Wih = (const float*)d_in[1];  // [20,1]
    const float* Whh = (const float*)d_in[2];  // [20,5]
    const float* bih = (const float*)d_in[3];  // [20]
    const float* bhh = (const float*)d_in[4];  // [20]
    float* out = (float*)d_out;                // [1,B,5]

    int* lengths = (int*)d_ws;                 // [0, Bn)
    int* perm    = lengths + Bn;               // [Bn, 2Bn)
    int* gbins   = perm + Bn;                  // [2Bn, 2Bn+NBINS)

    // Host-side base-G coefficients (pure CPU, ~us).
    GCoef GC;
    {
        double c14[16], c10[16];
        tanh_base_poly(14, c14);
        tanh_base_poly(10, c10);
        GC.q0  = (float)c14[0];  GC.q1  = (float)c14[1];
        GC.q2  = (float)c14[2];  GC.q3  = (float)c14[3];
        GC.q4  = (float)c14[4];  GC.q5  = (float)c14[5];
        GC.q6  = (float)c14[6];  GC.q7  = (float)c14[7];
        GC.q8  = (float)c14[8];  GC.q9  = (float)c14[9];
        GC.q10 = (float)c14[10]; GC.q11 = (float)c14[11];
        GC.q12 = (float)c14[12]; GC.q13 = (float)c14[13];
        GC.g0  = (float)c10[0];  GC.g1  = (float)c10[1];
        GC.g2  = (float)c10[2];  GC.g3  = (float)c10[3];
        GC.g4  = (float)c10[4];  GC.g5  = (float)c10[5];
        GC.g6  = (float)c10[6];  GC.g7  = (float)c10[7];
        GC.g8  = (float)c10[8];  GC.g9  = (float)c10[9];
    }

    zero_kernel<<<NBINS / 256, 256, 0, stream>>>(gbins);
    len_kernel<<<Bn / 4, 256, 0, stream>>>(x, lengths, gbins);
    sort_kernel<<<1, 1024, 0, stream>>>(lengths, gbins, perm);
    lstm_kernel<<<Bn * 8 / 256, 256, 0, stream>>>(x, Wih, Whh, bih, bhh,
                                                  lengths, perm, out, GC);
}